// Round 3
// baseline (92.090 us; speedup 1.0000x reference)
//
#include <hip/hip_runtime.h>

// CapsNet conv + dynamic routing (MI355X / gfx950).
// 3-kernel pipeline: prep (fp32->bf16 W + im2col into d_ws), fused main
// (MFMA conv, votes resident in accumulators, 3 routing iterations),
// epilogue (coalesced output transpose). Fallback: self-contained kernel.

#define BS 16
#define CI 256
#define CO 32
#define NO 8
#define HI 20
#define WI 20
#define HO 6
#define WO 6
#define NTAP 81
#define KPAD 104        // im2col K pitch (bf16): 16B-aligned rows, 2-way banks (free)
#define KW 96           // W row pitch (bf16)
#define NPIX (HO * WO)  // 36
#define NBLK (BS * NPIX) // 576

#define WS_WB_OFF   0
#define WS_ACT_OFF  65536
#define WS_XCOL_OFF 1048576
#define WS_FULL_NEED (WS_XCOL_OFF + (size_t)NBLK * CI * KPAD * 2)

typedef __attribute__((ext_vector_type(8))) short bf16x8;
typedef __attribute__((ext_vector_type(4))) float f32x4;

__device__ __forceinline__ ushort f2bf(float x) {
    union { float f; unsigned u; } v; v.f = x;
    unsigned r = v.u + 0x7FFFu + ((v.u >> 16) & 1u);   // RNE
    return (ushort)(r >> 16);
}

#define GLOAD_LDS16(g, l) __builtin_amdgcn_global_load_lds( \
    (const __attribute__((address_space(1))) unsigned int*)(g), \
    (__attribute__((address_space(3))) unsigned int*)(l), 16, 0, 0)

// ---------------- prep: W->bf16 [256][96], im2col x -> [blk][i][104] bf16 ----
__global__ __launch_bounds__(256) void prep_kernel(
    const float* __restrict__ x, const float* __restrict__ Wt,
    ushort* __restrict__ wb, ushort* __restrict__ xcol)
{
    const int blk = blockIdx.x, t = threadIdx.x;
    if (blk < CO * NO && t < KW)
        wb[blk * KW + t] = (t < NTAP) ? f2bf(Wt[blk * NTAP + t]) : (ushort)0;

    const int b = blk / NPIX, hw = blk % NPIX, h = hw / WO, w = hw % WO;
    const float* src = x + ((b * CI + t) * HI + 2 * h) * WI + 2 * w;
    unsigned rw[KPAD / 2];
    #pragma unroll
    for (int j = 0; j < KPAD / 2; ++j) rw[j] = 0u;
    #pragma unroll
    for (int kh = 0; kh < 9; ++kh)
        #pragma unroll
        for (int kw = 0; kw < 9; ++kw) {
            const int k = kh * 9 + kw;
            rw[k >> 1] |= ((unsigned)f2bf(src[kh * WI + kw])) << ((k & 1) * 16);
        }
    uint4* dst = (uint4*)(xcol + ((size_t)blk * CI + t) * KPAD);
    #pragma unroll
    for (int d = 0; d < KPAD / 8; ++d) {
        uint4 v; v.x = rw[4*d]; v.y = rw[4*d+1]; v.z = rw[4*d+2]; v.w = rw[4*d+3];
        dst[d] = v;
    }
}

// ---------------- main fused kernel (fast path) ------------------------------
// acc[tf][ti].r = votes[ i = 64*wi+16*ti+il ][ f = 64*wf+16*tf+4*q+r ]
__global__ __launch_bounds__(1024) void caps_main_fast(
    const ushort* __restrict__ wb, const ushort* __restrict__ xcol,
    const float* __restrict__ bias, float* __restrict__ actbuf)
{
    __shared__ __align__(16) ushort xw[CI * KPAD];   // 53248 B
    __shared__ __align__(16) float  smx[4 * 256];
    __shared__ __align__(16) float  pre[4 * 256];
    __shared__ __align__(16) float  act[256];

    const int t = threadIdx.x, blk = blockIdx.x;
    const int wid = t >> 6, l = t & 63;
    const int q = l >> 4, il = l & 15;
    const int wf = wid >> 2, wi = wid & 3;

    // W fragments straight from global (L2-resident, overlapped with staging)
    bf16x8 af[3][4];
    #pragma unroll
    for (int ks = 0; ks < 3; ++ks)
        #pragma unroll
        for (int tf = 0; tf < 4; ++tf)
            af[ks][tf] = *(const bf16x8*)&wb[(wf * 64 + tf * 16 + il) * KW + ks * 32 + q * 8];

    // linear 53248 B global->LDS copy (3 full passes + 4 KB by waves 0..3)
    {
        const char* src = (const char*)(xcol + (size_t)blk * CI * KPAD);
        char* lds = (char*)xw;
        #pragma unroll
        for (int p = 0; p < 3; ++p)
            GLOAD_LDS16(src + p * 16384 + wid * 1024 + l * 16,
                        lds + p * 16384 + wid * 1024);
        if (wid < 4)
            GLOAD_LDS16(src + 49152 + wid * 1024 + l * 16,
                        lds + 49152 + wid * 1024);
    }

    const float bias_r = (t < 256) ? bias[t] : 0.f;
    __syncthreads();

    // conv via MFMA
    f32x4 acc[4][4];
    #pragma unroll
    for (int tf = 0; tf < 4; ++tf)
        #pragma unroll
        for (int ti = 0; ti < 4; ++ti)
            acc[tf][ti] = (f32x4){0.f, 0.f, 0.f, 0.f};

    #pragma unroll
    for (int ks = 0; ks < 3; ++ks) {
        const int ko = ks * 32 + q * 8;
        bf16x8 bv[4];
        #pragma unroll
        for (int ti = 0; ti < 4; ++ti)
            bv[ti] = *(const bf16x8*)&xw[(wi * 64 + ti * 16 + il) * KPAD + ko];
        #pragma unroll
        for (int tf = 0; tf < 4; ++tf)
            #pragma unroll
            for (int ti = 0; ti < 4; ++ti)
                acc[tf][ti] = __builtin_amdgcn_mfma_f32_16x16x32_bf16(
                    af[ks][tf], bv[ti], acc[tf][ti], 0, 0, 0);
    }

    // routing (3 iterations) — same algebra as verified R2 kernel
    float lg[4][4];
    #pragma unroll
    for (int tf = 0; tf < 4; ++tf)
        #pragma unroll
        for (int ti = 0; ti < 4; ++ti) lg[tf][ti] = 0.f;

    #pragma unroll
    for (int it = 0; it < 3; ++it) {
        float route[4][4];
        if (it == 0) {
            #pragma unroll
            for (int tf = 0; tf < 4; ++tf)
                #pragma unroll
                for (int ti = 0; ti < 4; ++ti) route[tf][ti] = 0.03125f;
        } else {
            float e[4][4], srow[4] = {0.f, 0.f, 0.f, 0.f};
            #pragma unroll
            for (int tf = 0; tf < 4; ++tf)
                #pragma unroll
                for (int ti = 0; ti < 4; ++ti) {
                    e[tf][ti] = __expf(lg[tf][ti]);
                    srow[ti] += e[tf][ti];
                }
            #pragma unroll
            for (int ti = 0; ti < 4; ++ti)
                srow[ti] += __shfl_xor(srow[ti], 32, 64);
            if (q == 0) {
                #pragma unroll
                for (int ti = 0; ti < 4; ++ti)
                    smx[wf * 256 + wi * 64 + ti * 16 + il] = srow[ti];
            }
            __syncthreads();
            float rtot[4];
            #pragma unroll
            for (int ti = 0; ti < 4; ++ti) {
                int i = wi * 64 + ti * 16 + il;
                rtot[ti] = 1.0f / (smx[i] + smx[256 + i] + smx[512 + i] + smx[768 + i]);
            }
            #pragma unroll
            for (int tf = 0; tf < 4; ++tf)
                #pragma unroll
                for (int ti = 0; ti < 4; ++ti) route[tf][ti] = e[tf][ti] * rtot[ti];
        }

        float pp[4][4];
        #pragma unroll
        for (int tf = 0; tf < 4; ++tf)
            #pragma unroll
            for (int r = 0; r < 4; ++r)
                pp[tf][r] = route[tf][0] * acc[tf][0][r] + route[tf][1] * acc[tf][1][r]
                          + route[tf][2] * acc[tf][2][r] + route[tf][3] * acc[tf][3][r];
        #pragma unroll
        for (int m = 1; m <= 8; m <<= 1)
            #pragma unroll
            for (int tf = 0; tf < 4; ++tf)
                #pragma unroll
                for (int r = 0; r < 4; ++r)
                    pp[tf][r] += __shfl_xor(pp[tf][r], m, 64);
        if (il == 0) {
            #pragma unroll
            for (int tf = 0; tf < 4; ++tf) {
                int c = wf * 8 + tf * 2 + (q >> 1);
                f32x4 vv = {pp[tf][0], pp[tf][1], pp[tf][2], pp[tf][3]};
                *(f32x4*)&pre[wi * 256 + c * 8 + (q & 1) * 4] = vv;
            }
        }
        __syncthreads();

        if (t < 256) {
            float s = bias_r + pre[t] + pre[256 + t] + pre[512 + t] + pre[768 + t];
            float sq = s * s;
            sq += __shfl_xor(sq, 1, 64);
            sq += __shfl_xor(sq, 2, 64);
            sq += __shfl_xor(sq, 4, 64);
            float a = s * sqrtf(sq) / (1.f + sq);
            if (it == 2) actbuf[blk * 256 + t] = a;   // coalesced; epilogue transposes
            else act[t] = a;
        }
        __syncthreads();

        if (it < 2) {
            #pragma unroll
            for (int tf = 0; tf < 4; ++tf) {
                int c = wf * 8 + tf * 2 + (q >> 1);
                f32x4 av = *(const f32x4*)&act[c * 8 + (q & 1) * 4];
                #pragma unroll
                for (int ti = 0; ti < 4; ++ti) {
                    float d = acc[tf][ti][0] * av[0] + acc[tf][ti][1] * av[1]
                            + acc[tf][ti][2] * av[2] + acc[tf][ti][3] * av[3];
                    d += __shfl_xor(d, 16, 64);
                    lg[tf][ti] += d;
                }
            }
        }
    }
}

// ---------------- epilogue: [b][hw][cn] -> [b][c][n][h][w], coalesced writes --
__global__ __launch_bounds__(256) void epi_kernel(
    const float* __restrict__ actbuf, float* __restrict__ out)
{
    const int idx = blockIdx.x * 256 + threadIdx.x;       // 147456
    const int w = idx % WO, t1 = idx / WO;
    const int h = t1 % HO, t2 = t1 / HO;
    const int n = t2 % NO, t3 = t2 / NO;
    const int c = t3 % CO, b = t3 / CO;
    out[idx] = actbuf[(b * NPIX + h * WO + w) * 256 + c * 8 + n];
}

// ---------------- fallback: self-contained (verified R2 kernel) --------------
__global__ __launch_bounds__(1024) void caps_mfma_kernel(
    const float* __restrict__ x, const float* __restrict__ Wt,
    const float* __restrict__ bias, float* __restrict__ out)
{
    __shared__ __align__(16) ushort xw[CI * KPAD];
    __shared__ __align__(16) ushort wl[CO * NO * KPAD];
    __shared__ __align__(16) float  smx[4 * 256];
    __shared__ __align__(16) float  pre[4 * 256];
    __shared__ __align__(16) float  act[256];

    const int t = threadIdx.x, blk = blockIdx.x;
    const int b = blk / NPIX, hw = blk % NPIX, h = hw / WO, w = hw % WO;

    for (int p = t; p < CI * 9; p += 1024) {
        int i = p / 9, kh = p - i * 9;
        const float* src = x + ((b * CI + i) * HI + (2 * h + kh)) * WI + 2 * w;
        #pragma unroll
        for (int kw = 0; kw < 9; ++kw)
            xw[i * KPAD + kh * 9 + kw] = f2bf(src[kw]);
    }
    for (int p = t; p < CO * NO * NTAP; p += 1024) {
        int f = p / NTAP, k = p - f * NTAP;
        wl[f * KPAD + k] = f2bf(Wt[p]);
    }
    for (int p = t; p < 256 * (KPAD - NTAP); p += 1024) {
        int i = p / (KPAD - NTAP), k = NTAP + (p - i * (KPAD - NTAP));
        xw[i * KPAD + k] = 0;
        wl[i * KPAD + k] = 0;
    }
    const int wid = t >> 6, l = t & 63, q = l >> 4, il = l & 15;
    const int wf = wid >> 2, wi = wid & 3;
    const float bias_r = (t < 256) ? bias[t] : 0.f;
    __syncthreads();

    f32x4 acc[4][4];
    #pragma unroll
    for (int tf = 0; tf < 4; ++tf)
        #pragma unroll
        for (int ti = 0; ti < 4; ++ti) acc[tf][ti] = (f32x4){0.f, 0.f, 0.f, 0.f};
    #pragma unroll
    for (int ks = 0; ks < 3; ++ks) {
        const int ko = ks * 32 + q * 8;
        bf16x8 af[4], bv[4];
        #pragma unroll
        for (int tf = 0; tf < 4; ++tf)
            af[tf] = *(const bf16x8*)&wl[(wf * 64 + tf * 16 + il) * KPAD + ko];
        #pragma unroll
        for (int ti = 0; ti < 4; ++ti)
            bv[ti] = *(const bf16x8*)&xw[(wi * 64 + ti * 16 + il) * KPAD + ko];
        #pragma unroll
        for (int tf = 0; tf < 4; ++tf)
            #pragma unroll
            for (int ti = 0; ti < 4; ++ti)
                acc[tf][ti] = __builtin_amdgcn_mfma_f32_16x16x32_bf16(
                    af[tf], bv[ti], acc[tf][ti], 0, 0, 0);
    }

    float lg[4][4];
    #pragma unroll
    for (int tf = 0; tf < 4; ++tf)
        #pragma unroll
        for (int ti = 0; ti < 4; ++ti) lg[tf][ti] = 0.f;

    #pragma unroll
    for (int it = 0; it < 3; ++it) {
        float route[4][4];
        if (it == 0) {
            #pragma unroll
            for (int tf = 0; tf < 4; ++tf)
                #pragma unroll
                for (int ti = 0; ti < 4; ++ti) route[tf][ti] = 0.03125f;
        } else {
            float e[4][4], srow[4] = {0.f, 0.f, 0.f, 0.f};
            #pragma unroll
            for (int tf = 0; tf < 4; ++tf)
                #pragma unroll
                for (int ti = 0; ti < 4; ++ti) {
                    e[tf][ti] = __expf(lg[tf][ti]);
                    srow[ti] += e[tf][ti];
                }
            #pragma unroll
            for (int ti = 0; ti < 4; ++ti) srow[ti] += __shfl_xor(srow[ti], 32, 64);
            if (q == 0) {
                #pragma unroll
                for (int ti = 0; ti < 4; ++ti)
                    smx[wf * 256 + wi * 64 + ti * 16 + il] = srow[ti];
            }
            __syncthreads();
            float rtot[4];
            #pragma unroll
            for (int ti = 0; ti < 4; ++ti) {
                int i = wi * 64 + ti * 16 + il;
                rtot[ti] = 1.0f / (smx[i] + smx[256 + i] + smx[512 + i] + smx[768 + i]);
            }
            #pragma unroll
            for (int tf = 0; tf < 4; ++tf)
                #pragma unroll
                for (int ti = 0; ti < 4; ++ti) route[tf][ti] = e[tf][ti] * rtot[ti];
        }
        float pp[4][4];
        #pragma unroll
        for (int tf = 0; tf < 4; ++tf)
            #pragma unroll
            for (int r = 0; r < 4; ++r)
                pp[tf][r] = route[tf][0] * acc[tf][0][r] + route[tf][1] * acc[tf][1][r]
                          + route[tf][2] * acc[tf][2][r] + route[tf][3] * acc[tf][3][r];
        #pragma unroll
        for (int m = 1; m <= 8; m <<= 1)
            #pragma unroll
            for (int tf = 0; tf < 4; ++tf)
                #pragma unroll
                for (int r = 0; r < 4; ++r)
                    pp[tf][r] += __shfl_xor(pp[tf][r], m, 64);
        if (il == 0) {
            #pragma unroll
            for (int tf = 0; tf < 4; ++tf) {
                int c = wf * 8 + tf * 2 + (q >> 1);
                f32x4 vv = {pp[tf][0], pp[tf][1], pp[tf][2], pp[tf][3]};
                *(f32x4*)&pre[wi * 256 + c * 8 + (q & 1) * 4] = vv;
            }
        }
        __syncthreads();
        if (t < 256) {
            float s = bias_r + pre[t] + pre[256 + t] + pre[512 + t] + pre[768 + t];
            float sq = s * s;
            sq += __shfl_xor(sq, 1, 64);
            sq += __shfl_xor(sq, 2, 64);
            sq += __shfl_xor(sq, 4, 64);
            float a = s * sqrtf(sq) / (1.f + sq);
            if (it == 2) {
                int c = t >> 3, n = t & 7;
                out[(((b * CO + c) * NO + n) * HO + h) * WO + w] = a;
            } else act[t] = a;
        }
        __syncthreads();
        if (it < 2) {
            #pragma unroll
            for (int tf = 0; tf < 4; ++tf) {
                int c = wf * 8 + tf * 2 + (q >> 1);
                f32x4 av = *(const f32x4*)&act[c * 8 + (q & 1) * 4];
                #pragma unroll
                for (int ti = 0; ti < 4; ++ti) {
                    float d = acc[tf][ti][0] * av[0] + acc[tf][ti][1] * av[1]
                            + acc[tf][ti][2] * av[2] + acc[tf][ti][3] * av[3];
                    d += __shfl_xor(d, 16, 64);
                    lg[tf][ti] += d;
                }
            }
        }
    }
}

extern "C" void kernel_launch(void* const* d_in, const int* in_sizes, int n_in,
                              void* d_out, int out_size, void* d_ws, size_t ws_size,
                              hipStream_t stream) {
    const float* x    = (const float*)d_in[0];
    const float* Wt   = (const float*)d_in[1];
    const float* bias = (const float*)d_in[2];
    float* out = (float*)d_out;

    if (ws_size >= WS_FULL_NEED) {
        ushort* wb     = (ushort*)((char*)d_ws + WS_WB_OFF);
        float*  actbuf = (float*) ((char*)d_ws + WS_ACT_OFF);
        ushort* xcol   = (ushort*)((char*)d_ws + WS_XCOL_OFF);
        prep_kernel<<<NBLK, 256, 0, stream>>>(x, Wt, wb, xcol);
        caps_main_fast<<<NBLK, 1024, 0, stream>>>(wb, xcol, bias, actbuf);
        epi_kernel<<<NBLK, 256, 0, stream>>>(actbuf, out);
    } else {
        caps_mfma_kernel<<<NBLK, 1024, 0, stream>>>(x, Wt, bias, out);
    }
}

// Round 4
// 92.041 us; speedup vs baseline: 1.0005x; 1.0005x over previous
//
#include <hip/hip_runtime.h>

// CapsNet conv + dynamic routing, single fused kernel (MI355X / gfx950).
// grid = 192 blocks x 1024 threads; each block owns 3 consecutive pixels of
// one batch image. Per pixel: bf16 MFMA conv (votes^T resident in the 64-reg
// accumulator), 3 routing iterations with per-lane redundant squash.
// Staging of pixel p+1 is issued before routing of pixel p (overlap).
//
// Lane decomposition (l = lane, q = l>>4, il = l&15), wave (wf, wi):
//   acc[tf][ti].r = votes[ i = 64*wi+16*ti+il ][ f = 64*wf+16*tf+4*q+r ]
//   c = 8*wf + 2*tf + (q>>1)   (capsule),  n = 4*(q&1) + r

#define BS 16
#define CI 256
#define CO 32
#define NO 8
#define HI 20
#define WI 20
#define HO 6
#define WO 6
#define NPIX 36
#define NTAP 81
#define XP 104          // k pitch (bf16) for both x and W tiles (2-way banks, free)
#define PPB 3           // pixels per block
#define NBLK 192

typedef __attribute__((ext_vector_type(8))) short bf16x8;
typedef __attribute__((ext_vector_type(4))) float f32x4;

__device__ __forceinline__ ushort f2bf(float x) {
    union { float f; unsigned u; } v; v.f = x;
    unsigned r = v.u + 0x7FFFu + ((v.u >> 16) & 1u);   // RNE
    return (ushort)(r >> 16);
}

__global__ __launch_bounds__(1024) void caps_kernel(
    const float* __restrict__ x,     // [16,256,1,20,20]
    const float* __restrict__ Wt,    // [256,1,9,9]
    const float* __restrict__ bias,  // [32,8,1,1]
    float* __restrict__ out)         // [16,32,8,6,6]
{
    __shared__ __align__(16) ushort xw[CI * XP];        // 53248 B
    __shared__ __align__(16) ushort wl[CO * NO * XP];   // 53248 B
    __shared__ __align__(16) float  smx[4 * 256];       // softmax partials [wf][i]
    __shared__ __align__(16) float  pre[4 * 256];       // preact partials [wi][c*8+n]
    __shared__ __align__(16) float  outb[PPB * 256];    // staged outputs

    const int t   = threadIdx.x, blk = blockIdx.x;
    const int b   = blk / 12;             // 36/3 = 12 blocks per image
    const int hw0 = (blk % 12) * 3;

    const int wid = t >> 6, l = t & 63;
    const int q = l >> 4, il = l & 15;
    const int wf = wid >> 2, wi = wid & 3;

    // ---- W staging (once per block), k-major pitch 104
    for (int p = t; p < CO * NO * NTAP; p += 1024) {
        int f = p / NTAP, k = p - f * NTAP;
        wl[f * XP + k] = f2bf(Wt[p]);
    }
    // ---- zero pads k in [81,104) for both tiles (256 rows each, 4 threads/row)
    {
        int i = t >> 2, s4 = t & 3;
        #pragma unroll
        for (int j = 0; j < 6; ++j) {
            int k = NTAP + s4 * 6 + j;
            if (k < XP) { xw[i * XP + k] = 0; wl[i * XP + k] = 0; }
        }
    }
    // ---- stage x for pixel 0
    {
        const int h = hw0 / WO, w = hw0 % WO;
        for (int p = t; p < CI * 9; p += 1024) {
            int i = p / 9, kh = p - i * 9;
            const float* src = x + ((b * CI + i) * HI + (2 * h + kh)) * WI + 2 * w;
            #pragma unroll
            for (int kw = 0; kw < 9; ++kw)
                xw[i * XP + kh * 9 + kw] = f2bf(src[kw]);
        }
    }
    // ---- per-lane bias: bias[c*8 + 4*(q&1) + r] for this lane's 4 c's
    f32x4 bias_v[4];
    #pragma unroll
    for (int tf = 0; tf < 4; ++tf)
        bias_v[tf] = *(const f32x4*)&bias[(wf * 8 + tf * 2 + (q >> 1)) * 8 + 4 * (q & 1)];

    for (int pix = 0; pix < PPB; ++pix) {
        __syncthreads();   // staging of this pixel done; prev routing reads done

        // ---- conv via MFMA (votes^T)
        f32x4 acc[4][4];
        #pragma unroll
        for (int tf = 0; tf < 4; ++tf)
            #pragma unroll
            for (int ti = 0; ti < 4; ++ti)
                acc[tf][ti] = (f32x4){0.f, 0.f, 0.f, 0.f};
        #pragma unroll
        for (int ks = 0; ks < 3; ++ks) {
            const int ko = ks * 32 + q * 8;
            bf16x8 af[4], bv[4];
            #pragma unroll
            for (int tf = 0; tf < 4; ++tf)
                af[tf] = *(const bf16x8*)&wl[(wf * 64 + tf * 16 + il) * XP + ko];
            #pragma unroll
            for (int ti = 0; ti < 4; ++ti)
                bv[ti] = *(const bf16x8*)&xw[(wi * 64 + ti * 16 + il) * XP + ko];
            #pragma unroll
            for (int tf = 0; tf < 4; ++tf)
                #pragma unroll
                for (int ti = 0; ti < 4; ++ti)
                    acc[tf][ti] = __builtin_amdgcn_mfma_f32_16x16x32_bf16(
                        af[tf], bv[ti], acc[tf][ti], 0, 0, 0);
        }

        __syncthreads();   // conv reads of xw complete

        // ---- stage next pixel's x now; overlaps the routing below
        if (pix + 1 < PPB) {
            const int hwn = hw0 + pix + 1;
            const int h = hwn / WO, w = hwn % WO;
            for (int p = t; p < CI * 9; p += 1024) {
                int i = p / 9, kh = p - i * 9;
                const float* src = x + ((b * CI + i) * HI + (2 * h + kh)) * WI + 2 * w;
                #pragma unroll
                for (int kw = 0; kw < 9; ++kw)
                    xw[i * XP + kh * 9 + kw] = f2bf(src[kw]);
            }
        }

        // ---- dynamic routing, 3 iterations
        float lg[4][4];
        #pragma unroll
        for (int tf = 0; tf < 4; ++tf)
            #pragma unroll
            for (int ti = 0; ti < 4; ++ti) lg[tf][ti] = 0.f;

        #pragma unroll
        for (int it = 0; it < 3; ++it) {
            // --- route = softmax over c
            float route[4][4];
            if (it == 0) {
                #pragma unroll
                for (int tf = 0; tf < 4; ++tf)
                    #pragma unroll
                    for (int ti = 0; ti < 4; ++ti) route[tf][ti] = 0.03125f;
            } else {
                float e[4][4], srow[4] = {0.f, 0.f, 0.f, 0.f};
                #pragma unroll
                for (int tf = 0; tf < 4; ++tf)
                    #pragma unroll
                    for (int ti = 0; ti < 4; ++ti) {
                        e[tf][ti] = __expf(lg[tf][ti]);
                        srow[ti] += e[tf][ti];
                    }
                #pragma unroll
                for (int ti = 0; ti < 4; ++ti)
                    srow[ti] += __shfl_xor(srow[ti], 32, 64);   // other c-half (q>>1)
                if (q == 0) {
                    #pragma unroll
                    for (int ti = 0; ti < 4; ++ti)
                        smx[wf * 256 + wi * 64 + ti * 16 + il] = srow[ti];
                }
                __syncthreads();
                float rtot[4];
                #pragma unroll
                for (int ti = 0; ti < 4; ++ti) {
                    int i = wi * 64 + ti * 16 + il;
                    rtot[ti] = 1.0f / (smx[i] + smx[256 + i] + smx[512 + i] + smx[768 + i]);
                }
                #pragma unroll
                for (int tf = 0; tf < 4; ++tf)
                    #pragma unroll
                    for (int ti = 0; ti < 4; ++ti) route[tf][ti] = e[tf][ti] * rtot[ti];
            }

            // --- preact partials, reduce over in-lane ti then il lanes
            float pp[4][4];
            #pragma unroll
            for (int tf = 0; tf < 4; ++tf)
                #pragma unroll
                for (int r = 0; r < 4; ++r)
                    pp[tf][r] = route[tf][0] * acc[tf][0][r] + route[tf][1] * acc[tf][1][r]
                              + route[tf][2] * acc[tf][2][r] + route[tf][3] * acc[tf][3][r];
            #pragma unroll
            for (int m = 1; m <= 8; m <<= 1)
                #pragma unroll
                for (int tf = 0; tf < 4; ++tf)
                    #pragma unroll
                    for (int r = 0; r < 4; ++r)
                        pp[tf][r] += __shfl_xor(pp[tf][r], m, 64);
            if (il == 0) {
                #pragma unroll
                for (int tf = 0; tf < 4; ++tf) {
                    int c = wf * 8 + tf * 2 + (q >> 1);
                    f32x4 vv = {pp[tf][0], pp[tf][1], pp[tf][2], pp[tf][3]};
                    *(f32x4*)&pre[wi * 256 + c * 8 + (q & 1) * 4] = vv;
                }
            }
            __syncthreads();

            // --- per-lane redundant squash: act for this lane's (c, 4 n's)
            float av[4][4];
            #pragma unroll
            for (int tf = 0; tf < 4; ++tf) {
                const int c8 = (wf * 8 + tf * 2 + (q >> 1)) * 8 + (q & 1) * 4;
                f32x4 p0 = *(const f32x4*)&pre[c8];
                f32x4 p1 = *(const f32x4*)&pre[256 + c8];
                f32x4 p2 = *(const f32x4*)&pre[512 + c8];
                f32x4 p3 = *(const f32x4*)&pre[768 + c8];
                float s[4], sq4 = 0.f;
                #pragma unroll
                for (int r = 0; r < 4; ++r) {
                    s[r] = bias_v[tf][r] + p0[r] + p1[r] + p2[r] + p3[r];
                    sq4 += s[r] * s[r];
                }
                float sq = sq4 + __shfl_xor(sq4, 16, 64);   // other n-half
                float scale = sqrtf(sq) / (1.f + sq);
                #pragma unroll
                for (int r = 0; r < 4; ++r) av[tf][r] = s[r] * scale;
            }

            if (it < 2) {
                // --- distances -> logits (in-register act)
                #pragma unroll
                for (int tf = 0; tf < 4; ++tf)
                    #pragma unroll
                    for (int ti = 0; ti < 4; ++ti) {
                        float d = acc[tf][ti][0] * av[tf][0] + acc[tf][ti][1] * av[tf][1]
                                + acc[tf][ti][2] * av[tf][2] + acc[tf][ti][3] * av[tf][3];
                        d += __shfl_xor(d, 16, 64);
                        lg[tf][ti] += d;
                    }
            } else if (wi == 0 && il == 0) {
                // --- stage final activations to LDS (one writer per (c,n))
                #pragma unroll
                for (int tf = 0; tf < 4; ++tf) {
                    const int c8 = (wf * 8 + tf * 2 + (q >> 1)) * 8 + (q & 1) * 4;
                    #pragma unroll
                    for (int r = 0; r < 4; ++r)
                        outb[pix * 256 + c8 + r] = av[tf][r];
                }
            }
        }
    }

    __syncthreads();
    // ---- output: out[(b*256+cn)*36 + hw0 + pix], pix fastest for contiguity
    if (t < PPB * 256) {
        const int cn = t / 3, pix = t - cn * 3;
        out[(b * 256 + cn) * NPIX + hw0 + pix] = outb[pix * 256 + cn];
    }
}

extern "C" void kernel_launch(void* const* d_in, const int* in_sizes, int n_in,
                              void* d_out, int out_size, void* d_ws, size_t ws_size,
                              hipStream_t stream) {
    const float* x    = (const float*)d_in[0];
    const float* Wt   = (const float*)d_in[1];
    const float* bias = (const float*)d_in[2];
    float* out = (float*)d_out;
    caps_kernel<<<NBLK, 1024, 0, stream>>>(x, Wt, bias, out);
}